// Round 3
// baseline (301.376 us; speedup 1.0000x reference)
//
#include <hip/hip_runtime.h>
#include <cstdint>
#include <cstddef>

// B=8, N=2048, C=512
// out = feature + softmax(Q K^T) @ V / sqrt(C),  Q = X Wq^T + bq etc.
// Softmax without max subtraction (|scores| small): QK epilogue writes
// P = exp(S) bf16 + atomic row sums l; PV epilogue scales by scale/l[row].
// R3 change: BK 32 -> 64 in all GEMMs (halve barrier-drain count).

typedef __bf16 bf16x8 __attribute__((ext_vector_type(8)));
typedef float f32x4 __attribute__((ext_vector_type(4)));
typedef short short4v __attribute__((ext_vector_type(4)));
typedef short short8v __attribute__((ext_vector_type(8)));

__device__ __forceinline__ float b2f(short s) {
  union { float f; unsigned u; } u; u.u = ((unsigned)(unsigned short)s) << 16; return u.f;
}
__device__ __forceinline__ short f2b(float f) {
  union { float f; unsigned u; } u; u.f = f;
  unsigned r = (u.u + 0x7fffu + ((u.u >> 16) & 1u)) >> 16;  // RNE
  return (short)r;
}

#define GLDS(gptr, lptr) \
  __builtin_amdgcn_global_load_lds( \
      (const __attribute__((address_space(1))) unsigned int*)(const void*)(gptr), \
      (__attribute__((address_space(3))) unsigned int*)(void*)(lptr), 16, 0, 0)

// ---------------- fp32 -> bf16 conversions ----------------
__global__ __launch_bounds__(256) void cvt_f32_bf16(const float* __restrict__ src,
                                                    short* __restrict__ dst, int n4) {
  int i = blockIdx.x * 256 + threadIdx.x;
  if (i >= n4) return;
  float4 f = ((const float4*)src)[i];
  short4v o = { f2b(f.x), f2b(f.y), f2b(f.z), f2b(f.w) };
  *(short4v*)(dst + (size_t)i * 4) = o;
}

__global__ __launch_bounds__(256) void cvt_w3(const float* __restrict__ w0,
                                              const float* __restrict__ w1,
                                              const float* __restrict__ w2,
                                              short* __restrict__ dst) {
  int i = blockIdx.x * 256 + threadIdx.x;  // 0..196607
  const float* src = (i < 65536) ? w0 : (i < 131072) ? w1 : w2;
  int loc = i & 65535;
  float4 f = ((const float4*)src)[loc];
  short4v o = { f2b(f.x), f2b(f.y), f2b(f.z), f2b(f.w) };
  *(short4v*)(dst + (size_t)i * 4) = o;
}

__global__ __launch_bounds__(256) void pack_bias(const float* __restrict__ b0,
                                                 const float* __restrict__ b1,
                                                 const float* __restrict__ b2,
                                                 float* __restrict__ dst) {
  int t = blockIdx.x * 256 + threadIdx.x;  // 0..1535
  if (t >= 1536) return;
  const float* s = (t < 512) ? b0 : (t < 1024) ? b1 : b2;
  dst[t] = s[t & 511];
}

// ---------------- fused QKV projection: 128x128 tile, BK=64 ----------------
__global__ __launch_bounds__(256) void gemm_qkv(const short* __restrict__ A,
                                                const short* __restrict__ Wb,
                                                const float* __restrict__ biasP,
                                                short* __restrict__ Out) {
  __shared__ __align__(16) short As[128 * 64];
  __shared__ __align__(16) short Bs[128 * 64];
  const int z = blockIdx.z;
  const short* Bm = Wb + (size_t)z * 262144;
  const int m0 = blockIdx.y * 128, n0 = blockIdx.x * 128;
  const int t = threadIdx.x;
  const int lane = t & 63, w = t >> 6;
  const int wm = (w & 1) * 64, wn = (w >> 1) * 64;
  const int fr = lane & 15, fk = (lane >> 4) * 8;

  f32x4 acc[4][4] = {};

  for (int k0 = 0; k0 < 512; k0 += 64) {
    __syncthreads();
#pragma unroll
    for (int u = 0; u < 4; ++u) {
      int cc = t + u * 256;          // 1024 chunks of 16B per matrix
      int r = cc >> 3, k8 = (cc & 7) * 8;
      GLDS(A + (size_t)(m0 + r) * 512 + k0 + k8, As + cc * 8);
      GLDS(Bm + (size_t)(n0 + r) * 512 + k0 + k8, Bs + cc * 8);
    }
    __syncthreads();
#pragma unroll
    for (int h = 0; h < 2; ++h) {
      bf16x8 a[4], b[4];
#pragma unroll
      for (int i = 0; i < 4; ++i) a[i] = *(const bf16x8*)(As + (wm + i * 16 + fr) * 64 + h * 32 + fk);
#pragma unroll
      for (int j = 0; j < 4; ++j) b[j] = *(const bf16x8*)(Bs + (wn + j * 16 + fr) * 64 + h * 32 + fk);
#pragma unroll
      for (int i = 0; i < 4; ++i)
#pragma unroll
        for (int j = 0; j < 4; ++j)
          acc[i][j] = __builtin_amdgcn_mfma_f32_16x16x32_bf16(a[i], b[j], acc[i][j], 0, 0, 0);
    }
  }

  const int rq = (lane >> 4) * 4;
#pragma unroll
  for (int i = 0; i < 4; ++i)
#pragma unroll
    for (int j = 0; j < 4; ++j)
#pragma unroll
      for (int r = 0; r < 4; ++r) {
        int row = m0 + wm + i * 16 + rq + r;
        int col = n0 + wn + j * 16 + fr;
        Out[(size_t)z * 8388608 + (size_t)row * 512 + col] =
            f2b(acc[i][j][r] + biasP[z * 512 + col]);
      }
}

// ---------------- QK^T, 128x128 tile, BK=64, exp epilogue + atomic row sums ----------------
__global__ __launch_bounds__(256) void gemm_qk(const short* __restrict__ Q,
                                               const short* __restrict__ K,
                                               short* __restrict__ P,
                                               float* __restrict__ l) {
  __shared__ __align__(16) short As[128 * 64];
  __shared__ __align__(16) short Bs[128 * 64];
  const int z = blockIdx.z;
  const short* A = Q + (size_t)z * 2048 * 512;
  const short* Bm = K + (size_t)z * 2048 * 512;
  const int m0 = blockIdx.y * 128, n0 = blockIdx.x * 128;
  const int t = threadIdx.x;
  const int lane = t & 63, w = t >> 6;
  const int wm = (w & 1) * 64, wn = (w >> 1) * 64;
  const int fr = lane & 15, fk = (lane >> 4) * 8;

  f32x4 acc[4][4] = {};

  for (int k0 = 0; k0 < 512; k0 += 64) {
    __syncthreads();
#pragma unroll
    for (int u = 0; u < 4; ++u) {
      int cc = t + u * 256;
      int r = cc >> 3, k8 = (cc & 7) * 8;
      GLDS(A + (size_t)(m0 + r) * 512 + k0 + k8, As + cc * 8);
      GLDS(Bm + (size_t)(n0 + r) * 512 + k0 + k8, Bs + cc * 8);
    }
    __syncthreads();
#pragma unroll
    for (int h = 0; h < 2; ++h) {
      bf16x8 a[4], b[4];
#pragma unroll
      for (int i = 0; i < 4; ++i) a[i] = *(const bf16x8*)(As + (wm + i * 16 + fr) * 64 + h * 32 + fk);
#pragma unroll
      for (int j = 0; j < 4; ++j) b[j] = *(const bf16x8*)(Bs + (wn + j * 16 + fr) * 64 + h * 32 + fk);
#pragma unroll
      for (int i = 0; i < 4; ++i)
#pragma unroll
        for (int j = 0; j < 4; ++j)
          acc[i][j] = __builtin_amdgcn_mfma_f32_16x16x32_bf16(a[i], b[j], acc[i][j], 0, 0, 0);
    }
  }

  const int rq = (lane >> 4) * 4;
  float rs[4][4];
#pragma unroll
  for (int i = 0; i < 4; ++i)
#pragma unroll
    for (int r = 0; r < 4; ++r) rs[i][r] = 0.f;

#pragma unroll
  for (int i = 0; i < 4; ++i)
#pragma unroll
    for (int j = 0; j < 4; ++j)
#pragma unroll
      for (int r = 0; r < 4; ++r) {
        int row = m0 + wm + i * 16 + rq + r;
        int col = n0 + wn + j * 16 + fr;
        float e = exp2f(acc[i][j][r] * 1.4426950408889634f);
        short eb = f2b(e);
        P[(size_t)z * 4194304 + (size_t)row * 2048 + col] = eb;
        rs[i][r] += b2f(eb);
      }
#pragma unroll
  for (int i = 0; i < 4; ++i)
#pragma unroll
    for (int r = 0; r < 4; ++r) {
#pragma unroll
      for (int m = 1; m < 16; m <<= 1) rs[i][r] += __shfl_xor(rs[i][r], m);
    }
  if (fr == 0) {
#pragma unroll
    for (int i = 0; i < 4; ++i)
#pragma unroll
      for (int r = 0; r < 4; ++r)
        atomicAdd(&l[z * 2048 + m0 + wm + i * 16 + rq + r], rs[i][r]);
  }
}

// ---------------- PV: 64x128 tile, BK=64. out = resid + (P@V)*scale/l[row] ----------------
__global__ __launch_bounds__(256) void gemm_pv(const short* __restrict__ Pm,
                                               const short* __restrict__ Vt,
                                               const float* __restrict__ l,
                                               const float* __restrict__ resid,
                                               float* __restrict__ out, float scale) {
  __shared__ __align__(16) short As[64 * 64];    // 8 KB
  __shared__ __align__(16) short Bs[128 * 64];   // 16 KB
  const int z = blockIdx.z;
  const short* A = Pm + (size_t)z * 4194304;   // [2048][2048]
  const short* Bm = Vt + (size_t)z * 1048576;  // [512][2048]
  const int m0 = blockIdx.y * 64, n0 = blockIdx.x * 128;
  const int t = threadIdx.x;
  const int lane = t & 63, w = t >> 6;
  const int wm = (w & 1) * 32, wn = (w >> 1) * 64;
  const int fr = lane & 15, fk = (lane >> 4) * 8;

  f32x4 acc[2][4] = {};

  for (int k0 = 0; k0 < 2048; k0 += 64) {
    __syncthreads();
    {
      // A: 512 chunks (64 rows x 64 k), 2 per thread
#pragma unroll
      for (int u = 0; u < 2; ++u) {
        int cc = t + u * 256;
        int r = cc >> 3, k8 = (cc & 7) * 8;
        GLDS(A + (size_t)(m0 + r) * 2048 + k0 + k8, As + cc * 8);
      }
      // B: 1024 chunks (128 rows x 64 k), 4 per thread
#pragma unroll
      for (int u = 0; u < 4; ++u) {
        int cc = t + u * 256;
        int r = cc >> 3, k8 = (cc & 7) * 8;
        GLDS(Bm + (size_t)(n0 + r) * 2048 + k0 + k8, Bs + cc * 8);
      }
    }
    __syncthreads();
#pragma unroll
    for (int h = 0; h < 2; ++h) {
      bf16x8 a[2], b[4];
#pragma unroll
      for (int i = 0; i < 2; ++i) a[i] = *(const bf16x8*)(As + (wm + i * 16 + fr) * 64 + h * 32 + fk);
#pragma unroll
      for (int j = 0; j < 4; ++j) b[j] = *(const bf16x8*)(Bs + (wn + j * 16 + fr) * 64 + h * 32 + fk);
#pragma unroll
      for (int i = 0; i < 2; ++i)
#pragma unroll
        for (int j = 0; j < 4; ++j)
          acc[i][j] = __builtin_amdgcn_mfma_f32_16x16x32_bf16(a[i], b[j], acc[i][j], 0, 0, 0);
    }
  }

  const int rq = (lane >> 4) * 4;
#pragma unroll
  for (int i = 0; i < 2; ++i)
#pragma unroll
    for (int r = 0; r < 4; ++r) {
      int row = m0 + wm + i * 16 + rq + r;
      float linv = scale / l[z * 2048 + row];
#pragma unroll
      for (int j = 0; j < 4; ++j) {
        int col = n0 + wn + j * 16 + fr;
        size_t idx = (size_t)z * 1048576 + (size_t)row * 512 + col;
        out[idx] = resid[idx] + acc[i][j][r] * linv;
      }
    }
}

// ---------------- 64x64 LDS transpose: Vt[b][d][n] = V[b*2048+n][d] ----------------
__global__ __launch_bounds__(256) void transpose64(const short* __restrict__ V,
                                                   short* __restrict__ Vt) {
  __shared__ short tile[64][72];
  const int b = blockIdx.z;
  const int d0 = blockIdx.x * 64, n0 = blockIdx.y * 64;
  const int t = threadIdx.x;
#pragma unroll
  for (int h = 0; h < 2; ++h) {
    int c = t + h * 256;
    int r = c >> 3, cj = (c & 7) * 8;
    short8v val = *(const short8v*)(V + ((size_t)(b * 2048 + n0 + r)) * 512 + d0 + cj);
#pragma unroll
    for (int j = 0; j < 8; ++j) tile[r][cj + j] = val[j];
  }
  __syncthreads();
#pragma unroll
  for (int h = 0; h < 2; ++h) {
    int c = t + h * 256;
    int dr = c >> 3, nj = (c & 7) * 8;
    short8v o;
#pragma unroll
    for (int j = 0; j < 8; ++j) o[j] = tile[nj + j][dr];
    *(short8v*)(Vt + ((size_t)b * 512 + d0 + dr) * 2048 + n0 + nj) = o;
  }
}

extern "C" void kernel_launch(void* const* d_in, const int* in_sizes, int n_in,
                              void* d_out, int out_size, void* d_ws, size_t ws_size,
                              hipStream_t stream) {
  const float* feature = (const float*)d_in[0];
  const float* wq = (const float*)d_in[1];
  const float* bq = (const float*)d_in[2];
  const float* wk = (const float*)d_in[3];
  const float* bk = (const float*)d_in[4];
  const float* wv = (const float*)d_in[5];
  const float* bv = (const float*)d_in[6];
  float* out = (float*)d_out;

  const size_t MN = (size_t)16384 * 512;
  short* Xb = (short*)d_ws;       // MN
  short* Wb = Xb + MN;            // 3 * 262144
  short* Q = Wb + 786432;         // MN (K, V follow contiguously)
  short* K = Q + MN;
  short* V = K + MN;
  short* Vt = V + MN;             // [8][512][2048]
  short* P = Vt + MN;             // [8][2048][2048] unnormalized exp
  float* biasP = (float*)(P + (size_t)8 * 2048 * 2048);  // [3][512]
  float* l = biasP + 1536;        // [8*2048] row sums of exp

  cvt_f32_bf16<<<8192, 256, 0, stream>>>(feature, Xb, 2097152);
  cvt_w3<<<768, 256, 0, stream>>>(wq, wk, wv, Wb);
  pack_bias<<<6, 256, 0, stream>>>(bq, bk, bv, biasP);
  hipMemsetAsync(l, 0, 16384 * sizeof(float), stream);

  gemm_qkv<<<dim3(4, 128, 3), 256, 0, stream>>>(Xb, Wb, biasP, Q);
  transpose64<<<dim3(8, 32, 8), 256, 0, stream>>>(V, Vt);
  gemm_qk<<<dim3(16, 16, 8), 256, 0, stream>>>(Q, K, P, l);

  const float iscl = 0.044194173824159216f;  // 1/sqrt(512)
  gemm_pv<<<dim3(4, 32, 8), 256, 0, stream>>>(P, Vt, l, feature, out, iscl);
}

// Round 4
// 270.608 us; speedup vs baseline: 1.1137x; 1.1137x over previous
//
#include <hip/hip_runtime.h>
#include <cstdint>
#include <cstddef>

// B=8, N=2048, C=512
// out = feature + softmax(Q K^T) @ V / sqrt(C),  Q = X Wq^T + bq etc.
// Softmax without max subtraction; QK writes P=exp(S) bf16 + atomic row sums l;
// PV scales by scale/l[row].
// R4: revert to BK=32 (BK=64 caused 16-way LDS bank conflicts);
//     swap MFMA operands so acc reg-quads are contiguous in the output fast dim
//     -> vectorized epilogues (short4/float4); merge prep kernels into one.

typedef __bf16 bf16x8 __attribute__((ext_vector_type(8)));
typedef float f32x4 __attribute__((ext_vector_type(4)));
typedef short short4v __attribute__((ext_vector_type(4)));
typedef short short8v __attribute__((ext_vector_type(8)));

__device__ __forceinline__ float b2f(short s) {
  union { float f; unsigned u; } u; u.u = ((unsigned)(unsigned short)s) << 16; return u.f;
}
__device__ __forceinline__ short f2b(float f) {
  union { float f; unsigned u; } u; u.f = f;
  unsigned r = (u.u + 0x7fffu + ((u.u >> 16) & 1u)) >> 16;  // RNE
  return (short)r;
}

#define GLDS(gptr, lptr) \
  __builtin_amdgcn_global_load_lds( \
      (const __attribute__((address_space(1))) unsigned int*)(const void*)(gptr), \
      (__attribute__((address_space(3))) unsigned int*)(void*)(lptr), 16, 0, 0)

// ---------------- merged prep: feature->bf16, weights->bf16, bias pack, l=0 ----------------
__global__ __launch_bounds__(256) void prep(const float* __restrict__ f,
                                            const float* __restrict__ w0,
                                            const float* __restrict__ w1,
                                            const float* __restrict__ w2,
                                            const float* __restrict__ b0,
                                            const float* __restrict__ b1,
                                            const float* __restrict__ b2,
                                            short* __restrict__ Xb, short* __restrict__ Wb,
                                            float* __restrict__ biasP, float* __restrict__ l) {
  const int bid = blockIdx.x;
  const int t = threadIdx.x;
  if (bid < 8192) {                       // feature: 2097152 float4
    int i = bid * 256 + t;
    float4 v = ((const float4*)f)[i];
    short4v o = { f2b(v.x), f2b(v.y), f2b(v.z), f2b(v.w) };
    *(short4v*)(Xb + (size_t)i * 4) = o;
  } else if (bid < 8960) {                // weights: 196608 float4
    int i = (bid - 8192) * 256 + t;
    const float* src = (i < 65536) ? w0 : (i < 131072) ? w1 : w2;
    float4 v = ((const float4*)src)[i & 65535];
    short4v o = { f2b(v.x), f2b(v.y), f2b(v.z), f2b(v.w) };
    *(short4v*)(Wb + (size_t)i * 4) = o;
  } else {                                // 8 blocks: l zero (16384 f32) + bias (1536)
    int i = (bid - 8960) * 256 + t;       // 0..2047
    float4 z = { 0.f, 0.f, 0.f, 0.f };
    ((float4*)l)[i * 2] = z;
    ((float4*)l)[i * 2 + 1] = z;
    if (i < 1536) {
      const float* s = (i < 512) ? b0 : (i < 1024) ? b1 : b2;
      biasP[i] = s[i & 511];
    }
  }
}

// ---------------- fused QKV projection: 128x128 tile, BK=32, swapped operands ----------------
// A-operand = W rows (output dim n), B-operand = X rows (token m).
__global__ __launch_bounds__(256) void gemm_qkv(const short* __restrict__ X,
                                                const short* __restrict__ Wall,
                                                const float* __restrict__ biasP,
                                                short* __restrict__ Out) {
  __shared__ __align__(16) short Xs[128 * 32];
  __shared__ __align__(16) short Ws[128 * 32];
  const int z = blockIdx.z;
  const short* Wm = Wall + (size_t)z * 262144;
  const int m0 = blockIdx.y * 128, n0 = blockIdx.x * 128;
  const int t = threadIdx.x;
  const int lane = t & 63, w = t >> 6;
  const int wn = (w & 1) * 64, wm = (w >> 1) * 64;
  const int fr = lane & 15, fk = (lane >> 4) * 8;

  f32x4 acc[4][4] = {};  // [i over n][j over m]
  const int c0 = t, c1 = t + 256;
  const int r0 = c0 >> 2, k80 = (c0 & 3) * 8;
  const int r1 = c1 >> 2, k81 = (c1 & 3) * 8;

  for (int k0 = 0; k0 < 512; k0 += 32) {
    __syncthreads();
    GLDS(X + (size_t)(m0 + r0) * 512 + k0 + k80, Xs + c0 * 8);
    GLDS(X + (size_t)(m0 + r1) * 512 + k0 + k81, Xs + c1 * 8);
    GLDS(Wm + (size_t)(n0 + r0) * 512 + k0 + k80, Ws + c0 * 8);
    GLDS(Wm + (size_t)(n0 + r1) * 512 + k0 + k81, Ws + c1 * 8);
    __syncthreads();
    bf16x8 wf[4], xf[4];
#pragma unroll
    for (int i = 0; i < 4; ++i) wf[i] = *(const bf16x8*)(Ws + (wn + i * 16 + fr) * 32 + fk);
#pragma unroll
    for (int j = 0; j < 4; ++j) xf[j] = *(const bf16x8*)(Xs + (wm + j * 16 + fr) * 32 + fk);
#pragma unroll
    for (int i = 0; i < 4; ++i)
#pragma unroll
      for (int j = 0; j < 4; ++j)
        acc[i][j] = __builtin_amdgcn_mfma_f32_16x16x32_bf16(wf[i], xf[j], acc[i][j], 0, 0, 0);
  }

  // C-row = n (A side), C-col = m (B side): lane's reg quad = 4 consecutive n.
  const int rq = (lane >> 4) * 4;
#pragma unroll
  for (int i = 0; i < 4; ++i) {
    int nb = n0 + wn + i * 16 + rq;
    float4 bs = *(const float4*)(biasP + z * 512 + nb);
#pragma unroll
    for (int j = 0; j < 4; ++j) {
      int m = m0 + wm + j * 16 + fr;
      short4v o = { f2b(acc[i][j][0] + bs.x), f2b(acc[i][j][1] + bs.y),
                    f2b(acc[i][j][2] + bs.z), f2b(acc[i][j][3] + bs.w) };
      *(short4v*)(Out + (size_t)z * 8388608 + (size_t)m * 512 + nb) = o;
    }
  }
}

// ---------------- QK^T: 128x128 tile, BK=32, swapped operands, exp epilogue ----------------
// A-operand = K rows (key n), B-operand = Q rows (query m).
__global__ __launch_bounds__(256) void gemm_qk(const short* __restrict__ Q,
                                               const short* __restrict__ Kb,
                                               short* __restrict__ P,
                                               float* __restrict__ l) {
  __shared__ __align__(16) short Qs[128 * 32];
  __shared__ __align__(16) short Ks[128 * 32];
  const int z = blockIdx.z;
  const short* A = Q + (size_t)z * 2048 * 512;
  const short* Bm = Kb + (size_t)z * 2048 * 512;
  const int m0 = blockIdx.y * 128, n0 = blockIdx.x * 128;
  const int t = threadIdx.x;
  const int lane = t & 63, w = t >> 6;
  const int wn = (w & 1) * 64, wm = (w >> 1) * 64;
  const int fr = lane & 15, fk = (lane >> 4) * 8;

  f32x4 acc[4][4] = {};  // [i over keys][j over queries]
  const int c0 = t, c1 = t + 256;
  const int r0 = c0 >> 2, k80 = (c0 & 3) * 8;
  const int r1 = c1 >> 2, k81 = (c1 & 3) * 8;

  for (int k0 = 0; k0 < 512; k0 += 32) {
    __syncthreads();
    GLDS(A + (size_t)(m0 + r0) * 512 + k0 + k80, Qs + c0 * 8);
    GLDS(A + (size_t)(m0 + r1) * 512 + k0 + k81, Qs + c1 * 8);
    GLDS(Bm + (size_t)(n0 + r0) * 512 + k0 + k80, Ks + c0 * 8);
    GLDS(Bm + (size_t)(n0 + r1) * 512 + k0 + k81, Ks + c1 * 8);
    __syncthreads();
    bf16x8 kf[4], qf[4];
#pragma unroll
    for (int i = 0; i < 4; ++i) kf[i] = *(const bf16x8*)(Ks + (wn + i * 16 + fr) * 32 + fk);
#pragma unroll
    for (int j = 0; j < 4; ++j) qf[j] = *(const bf16x8*)(Qs + (wm + j * 16 + fr) * 32 + fk);
#pragma unroll
    for (int i = 0; i < 4; ++i)
#pragma unroll
      for (int j = 0; j < 4; ++j)
        acc[i][j] = __builtin_amdgcn_mfma_f32_16x16x32_bf16(kf[i], qf[j], acc[i][j], 0, 0, 0);
  }

  // C-row = key n (quad-contiguous), C-col = query m.
  const int rq = (lane >> 4) * 4;
  float rs[4] = { 0.f, 0.f, 0.f, 0.f };  // per query-subtile j, this lane's row m partial
#pragma unroll
  for (int i = 0; i < 4; ++i) {
    int nb = n0 + wn + i * 16 + rq;
#pragma unroll
    for (int j = 0; j < 4; ++j) {
      int m = m0 + wm + j * 16 + fr;
      short4v o;
      float part = 0.f;
#pragma unroll
      for (int r = 0; r < 4; ++r) {
        float e = exp2f(acc[i][j][r] * 1.4426950408889634f);
        short eb = f2b(e);
        o[r] = eb;
        part += b2f(eb);  // sum exactly what PV will consume
      }
      *(short4v*)(P + (size_t)z * 4194304 + (size_t)m * 2048 + nb) = o;
      rs[j] += part;
    }
  }
  // reduce across the 4 quad-groups (same m, different n-quads)
#pragma unroll
  for (int j = 0; j < 4; ++j) {
    rs[j] += __shfl_xor(rs[j], 16);
    rs[j] += __shfl_xor(rs[j], 32);
  }
  if (lane < 16) {
#pragma unroll
    for (int j = 0; j < 4; ++j)
      atomicAdd(&l[z * 2048 + m0 + wm + j * 16 + fr], rs[j]);
  }
}

// ---------------- PV: 64x128 (m x n) tile, BK=32, swapped operands ----------------
// A-operand = Vt rows (output dim n), B-operand = P rows (query m).
__global__ __launch_bounds__(256) void gemm_pv(const short* __restrict__ Pm,
                                               const short* __restrict__ Vt,
                                               const float* __restrict__ l,
                                               const float* __restrict__ resid,
                                               float* __restrict__ out, float scale) {
  __shared__ __align__(16) short Ps[64 * 32];    // 4 KB
  __shared__ __align__(16) short Vs[128 * 32];   // 8 KB
  const int z = blockIdx.z;
  const short* A = Pm + (size_t)z * 4194304;   // [2048][2048]
  const short* Bm = Vt + (size_t)z * 1048576;  // [512][2048]
  const int m0 = blockIdx.y * 64, n0 = blockIdx.x * 128;
  const int t = threadIdx.x;
  const int lane = t & 63, w = t >> 6;
  const int wn = (w & 1) * 64, wm = (w >> 1) * 32;
  const int fr = lane & 15, fk = (lane >> 4) * 8;

  f32x4 acc[4][2] = {};  // [i over n][j over m]
  const int ra = t >> 2, k8a = (t & 3) * 8;    // Ps: 256 chunks
  const int c0 = t, c1 = t + 256;              // Vs: 512 chunks
  const int r0 = c0 >> 2, k80 = (c0 & 3) * 8;
  const int r1 = c1 >> 2, k81 = (c1 & 3) * 8;

  for (int k0 = 0; k0 < 2048; k0 += 32) {
    __syncthreads();
    GLDS(A + (size_t)(m0 + ra) * 2048 + k0 + k8a, Ps + t * 8);
    GLDS(Bm + (size_t)(n0 + r0) * 2048 + k0 + k80, Vs + c0 * 8);
    GLDS(Bm + (size_t)(n0 + r1) * 2048 + k0 + k81, Vs + c1 * 8);
    __syncthreads();
    bf16x8 vf[4], pf[2];
#pragma unroll
    for (int i = 0; i < 4; ++i) vf[i] = *(const bf16x8*)(Vs + (wn + i * 16 + fr) * 32 + fk);
#pragma unroll
    for (int j = 0; j < 2; ++j) pf[j] = *(const bf16x8*)(Ps + (wm + j * 16 + fr) * 32 + fk);
#pragma unroll
    for (int i = 0; i < 4; ++i)
#pragma unroll
      for (int j = 0; j < 2; ++j)
        acc[i][j] = __builtin_amdgcn_mfma_f32_16x16x32_bf16(vf[i], pf[j], acc[i][j], 0, 0, 0);
  }

  // C-row = n (quad-contiguous -> float4 stores), C-col = m.
  const int rq = (lane >> 4) * 4;
#pragma unroll
  for (int j = 0; j < 2; ++j) {
    int m = m0 + wm + j * 16 + fr;
    float linv = scale / l[z * 2048 + m];
#pragma unroll
    for (int i = 0; i < 4; ++i) {
      int nb = n0 + wn + i * 16 + rq;
      size_t idx = (size_t)z * 1048576 + (size_t)m * 512 + nb;
      float4 rv = *(const float4*)(resid + idx);
      float4 o = { rv.x + acc[i][j][0] * linv, rv.y + acc[i][j][1] * linv,
                   rv.z + acc[i][j][2] * linv, rv.w + acc[i][j][3] * linv };
      *(float4*)(out + idx) = o;
    }
  }
}

// ---------------- 64x64 LDS transpose: Vt[b][d][n] = V[b*2048+n][d] ----------------
__global__ __launch_bounds__(256) void transpose64(const short* __restrict__ V,
                                                   short* __restrict__ Vt) {
  __shared__ short tile[64][72];
  const int b = blockIdx.z;
  const int d0 = blockIdx.x * 64, n0 = blockIdx.y * 64;
  const int t = threadIdx.x;
#pragma unroll
  for (int h = 0; h < 2; ++h) {
    int c = t + h * 256;
    int r = c >> 3, cj = (c & 7) * 8;
    short8v val = *(const short8v*)(V + ((size_t)(b * 2048 + n0 + r)) * 512 + d0 + cj);
#pragma unroll
    for (int j = 0; j < 8; ++j) tile[r][cj + j] = val[j];
  }
  __syncthreads();
#pragma unroll
  for (int h = 0; h < 2; ++h) {
    int c = t + h * 256;
    int dr = c >> 3, nj = (c & 7) * 8;
    short8v o;
#pragma unroll
    for (int j = 0; j < 8; ++j) o[j] = tile[nj + j][dr];
    *(short8v*)(Vt + ((size_t)b * 512 + d0 + dr) * 2048 + n0 + nj) = o;
  }
}

extern "C" void kernel_launch(void* const* d_in, const int* in_sizes, int n_in,
                              void* d_out, int out_size, void* d_ws, size_t ws_size,
                              hipStream_t stream) {
  const float* feature = (const float*)d_in[0];
  const float* wq = (const float*)d_in[1];
  const float* bq = (const float*)d_in[2];
  const float* wk = (const float*)d_in[3];
  const float* bk = (const float*)d_in[4];
  const float* wv = (const float*)d_in[5];
  const float* bv = (const float*)d_in[6];
  float* out = (float*)d_out;

  const size_t MN = (size_t)16384 * 512;
  short* Xb = (short*)d_ws;       // MN
  short* Wb = Xb + MN;            // 3 * 262144
  short* Q = Wb + 786432;         // MN (K, V follow contiguously)
  short* K = Q + MN;
  short* V = K + MN;
  short* Vt = V + MN;             // [8][512][2048]
  short* P = Vt + MN;             // [8][2048][2048] unnormalized exp
  float* biasP = (float*)(P + (size_t)8 * 2048 * 2048);  // [3][512]
  float* l = biasP + 1536;        // [8*2048] row sums of exp

  prep<<<8968, 256, 0, stream>>>(feature, wq, wk, wv, bq, bk, bv, Xb, Wb, biasP, l);

  gemm_qkv<<<dim3(4, 128, 3), 256, 0, stream>>>(Xb, Wb, biasP, Q);
  transpose64<<<dim3(8, 32, 8), 256, 0, stream>>>(V, Vt);
  gemm_qk<<<dim3(16, 16, 8), 256, 0, stream>>>(Q, K, P, l);

  const float iscl = 0.044194173824159216f;  // 1/sqrt(512)
  gemm_pv<<<dim3(4, 32, 8), 256, 0, stream>>>(P, Vt, l, feature, out, iscl);
}